// Round 1
// baseline (83.079 us; speedup 1.0000x reference)
//
#include <hip/hip_runtime.h>

// QuantumKernelMethod: out[i][j] = |phi(a_i)^dag M(b_j) phi(a_i)|
// phi = V(x)|0>, M = V(y) Z0 V(y)^dag. Reduced to real GEMM 1024x1024x512:
// out = |Q * M^T| with q_i = [Re Q, Im Q], m_j = [Re M, -Im M] (512 floats each).

#define NA 1024
#define NB 1024
#define KDIM 512

typedef __attribute__((ext_vector_type(8))) short bf16x8;
typedef __attribute__((ext_vector_type(4))) float f32x4;

__device__ __forceinline__ unsigned short f2bf(float x) {
    union { float f; unsigned u; } v; v.f = x;
    unsigned r = v.u + 0x7fffu + ((v.u >> 16) & 1u);  // RNE
    return (unsigned short)(r >> 16);
}

__device__ __forceinline__ uint4 pack8(const float* f) {
    uint4 u;
    u.x = (unsigned)f2bf(f[0]) | ((unsigned)f2bf(f[1]) << 16);
    u.y = (unsigned)f2bf(f[2]) | ((unsigned)f2bf(f[3]) << 16);
    u.z = (unsigned)f2bf(f[4]) | ((unsigned)f2bf(f[5]) << 16);
    u.w = (unsigned)f2bf(f[6]) | ((unsigned)f2bf(f[7]) << 16);
    return u;
}

// State: 16 complex amps, flat index = b0*8 + b1*4 + b2*2 + b3 (wire w -> bit 3-w)
__device__ __forceinline__ void ry_gate(float* sr, float* si, int w, float t) {
    float s, c; __sincosf(0.5f * t, &s, &c);
    int st = 8 >> w;
    #pragma unroll
    for (int b = 0; b < 16; ++b) {
        if (b & st) continue;
        int j = b | st;
        float r0 = sr[b], i0 = si[b], r1 = sr[j], i1 = si[j];
        sr[b] = c * r0 - s * r1;  si[b] = c * i0 - s * i1;
        sr[j] = s * r0 + c * r1;  si[j] = s * i0 + c * i1;
    }
}

__device__ __forceinline__ void rx_gate(float* sr, float* si, int w, float t) {
    float s, c; __sincosf(0.5f * t, &s, &c);
    int st = 8 >> w;
    #pragma unroll
    for (int b = 0; b < 16; ++b) {
        if (b & st) continue;
        int j = b | st;
        float r0 = sr[b], i0 = si[b], r1 = sr[j], i1 = si[j];
        // new0 = c*s0 - i s * s1 ; new1 = -i s * s0 + c * s1
        sr[b] = c * r0 + s * i1;  si[b] = c * i0 - s * r1;
        sr[j] = c * r1 + s * i0;  si[j] = c * i1 - s * r0;
    }
}

__device__ __forceinline__ void rz_gate(float* sr, float* si, int w, float t) {
    float s, c; __sincosf(0.5f * t, &s, &c);
    int st = 8 >> w;
    #pragma unroll
    for (int b = 0; b < 16; ++b) {
        if (b & st) continue;
        int j = b | st;
        float r0 = sr[b], i0 = si[b], r1 = sr[j], i1 = si[j];
        // bit=0: *(c - i s); bit=1: *(c + i s)
        sr[b] = c * r0 + s * i0;  si[b] = c * i0 - s * r0;
        sr[j] = c * r1 - s * i1;  si[j] = c * i1 + s * r1;
    }
}

__device__ __forceinline__ void cnot_gate(float* sr, float* si, int cw, int tw) {
    int cs = 8 >> cw, ts = 8 >> tw;
    #pragma unroll
    for (int b = 0; b < 16; ++b) {
        if ((b & cs) && !(b & ts)) {
            int j = b | ts;
            float tr = sr[b]; sr[b] = sr[j]; sr[j] = tr;
            float ti = si[b]; si[b] = si[j]; si[j] = ti;
        }
    }
}

__device__ __forceinline__ void ansatz(float* sr, float* si, const float* vec, const float* P) {
    #pragma unroll
    for (int q = 0; q < 4; ++q) ry_gate(sr, si, q, vec[q]);
    #pragma unroll
    for (int l = 0; l < 2; ++l) {
        #pragma unroll
        for (int q = 0; q < 4; ++q) {
            rx_gate(sr, si, q, P[l * 12 + q * 3 + 0]);
            ry_gate(sr, si, q, P[l * 12 + q * 3 + 1]);
            rz_gate(sr, si, q, P[l * 12 + q * 3 + 2]);
        }
        cnot_gate(sr, si, 0, 1);
        cnot_gate(sr, si, 1, 2);
        cnot_gate(sr, si, 2, 3);
        cnot_gate(sr, si, 3, 0);
    }
}

// Blocks [0,256): M-part, 4 y's per block (16 threads each simulate one basis col).
// Blocks [256,272): Q-part, 64 i's per block (one thread = one statevector sim).
__global__ __launch_bounds__(64) void qkm_phase1(
    const float* __restrict__ a, const float* __restrict__ b,
    const float* __restrict__ params,
    uint4* __restrict__ Qv, uint4* __restrict__ Mv) {
    float P[24];
    #pragma unroll
    for (int j = 0; j < 24; ++j) P[j] = params[j];
    int tid = threadIdx.x;
    int blk = blockIdx.x;

    if (blk < 256) {
        __shared__ float vr[4][16][17];
        __shared__ float vi[4][16][17];
        int yl = tid >> 4, p = tid & 15;
        int y = (blk << 2) + yl;
        float sr[16], si[16];
        #pragma unroll
        for (int k = 0; k < 16; ++k) { sr[k] = (k == p) ? 1.f : 0.f; si[k] = 0.f; }
        float vec[4];
        #pragma unroll
        for (int q = 0; q < 4; ++q) vec[q] = b[y * 4 + q];
        ansatz(sr, si, vec, P);
        #pragma unroll
        for (int k = 0; k < 16; ++k) { vr[yl][p][k] = sr[k]; vi[yl][p][k] = si[k]; }
        __syncthreads();
        // Thread computes row k=p of M_y: M[k][l] = sum_p d_p v_p[k] conj(v_p[l])
        int k = p;
        float mr[16], mi[16];
        #pragma unroll
        for (int l = 0; l < 16; ++l) { mr[l] = 0.f; mi[l] = 0.f; }
        #pragma unroll
        for (int p2 = 0; p2 < 16; ++p2) {
            float d = (p2 & 8) ? -1.f : 1.f;  // Z0 sign: wire-0 bit = bit 3
            float ar = vr[yl][p2][k], ai = vi[yl][p2][k];
            float dar = d * ar, dai = d * ai;
            #pragma unroll
            for (int l = 0; l < 16; ++l) {
                float br = vr[yl][p2][l], bi = vi[yl][p2][l];
                mr[l] += dar * br + dai * bi;   // d * Re(v_k conj(v_l))
                mi[l] += dai * br - dar * bi;   // d * Im(v_k conj(v_l))
            }
        }
        float ni[16];
        #pragma unroll
        for (int l = 0; l < 16; ++l) ni[l] = -mi[l];   // store -Im M
        uint4* d0 = Mv + y * 64 + k * 2;        // Re M at ushort offset k*16
        d0[0] = pack8(&mr[0]); d0[1] = pack8(&mr[8]);
        uint4* d1 = Mv + y * 64 + 32 + k * 2;   // -Im M at ushort offset 256+k*16
        d1[0] = pack8(&ni[0]); d1[1] = pack8(&ni[8]);
    } else {
        int i = ((blk - 256) << 6) + tid;
        float sr[16], si[16];
        #pragma unroll
        for (int k = 0; k < 16; ++k) { sr[k] = (k == 0) ? 1.f : 0.f; si[k] = 0.f; }
        float vec[4];
        #pragma unroll
        for (int q = 0; q < 4; ++q) vec[q] = a[i * 4 + q];
        ansatz(sr, si, vec, P);
        // Q[k][l] = conj(phi_k) phi_l: Re = rk*rl + ik*il, Im = rk*il - ik*rl
        #pragma unroll
        for (int k = 0; k < 16; ++k) {
            float t0[16], t1[16];
            float rk = sr[k], ik = si[k];
            #pragma unroll
            for (int l = 0; l < 16; ++l) {
                t0[l] = rk * sr[l] + ik * si[l];
                t1[l] = rk * si[l] - ik * sr[l];
            }
            uint4* d0 = Qv + i * 64 + k * 2;
            d0[0] = pack8(t0); d0[1] = pack8(t0 + 8);
            uint4* d1 = Qv + i * 64 + 32 + k * 2;
            d1[0] = pack8(t1); d1[1] = pack8(t1 + 8);
        }
    }
}

// Phase 2: out = |Q * M^T|, bf16 MFMA. Block = 4 waves in 2x2, 32x32 tile/block.
__global__ __launch_bounds__(256) void qkm_phase2(
    const unsigned short* __restrict__ Q, const unsigned short* __restrict__ M,
    float* __restrict__ out) {
    int wave = threadIdx.x >> 6;
    int lane = threadIdx.x & 63;
    int bi = blockIdx.x >> 5;        // 32 i-tiles
    int bj = blockIdx.x & 31;        // 32 j-tiles
    int wi = wave >> 1, wj = wave & 1;
    int row0 = bi * 32 + wi * 16;
    int col0 = bj * 32 + wj * 16;
    int m16 = lane & 15;
    int quad = lane >> 4;

    const unsigned short* qrow = Q + (row0 + m16) * KDIM + quad * 8;
    const unsigned short* mrow = M + (col0 + m16) * KDIM + quad * 8;

    f32x4 acc = {0.f, 0.f, 0.f, 0.f};
    #pragma unroll
    for (int kk = 0; kk < 16; ++kk) {
        bf16x8 afrag = *(const bf16x8*)(qrow + kk * 32);
        bf16x8 bfrag = *(const bf16x8*)(mrow + kk * 32);
        acc = __builtin_amdgcn_mfma_f32_16x16x32_bf16(afrag, bfrag, acc, 0, 0, 0);
    }
    // C/D layout: col = lane&15, row = quad*4 + r  [HW-verified]
    #pragma unroll
    for (int r = 0; r < 4; ++r) {
        int orow = row0 + quad * 4 + r;
        int ocol = col0 + m16;
        out[orow * NB + ocol] = fabsf(acc[r]);
    }
}

extern "C" void kernel_launch(void* const* d_in, const int* in_sizes, int n_in,
                              void* d_out, int out_size, void* d_ws, size_t ws_size,
                              hipStream_t stream) {
    const float* a = (const float*)d_in[0];       // 1024 x 4
    const float* b = (const float*)d_in[1];       // 1024 x 4
    const float* params = (const float*)d_in[2];  // 2 x 4 x 3
    float* out = (float*)d_out;                   // 1024 x 1024

    unsigned short* Q = (unsigned short*)d_ws;            // NA x 512 bf16
    unsigned short* M = Q + (size_t)NA * KDIM;            // NB x 512 bf16

    qkm_phase1<<<256 + NA / 64, 64, 0, stream>>>(a, b, params, (uint4*)Q, (uint4*)M);
    qkm_phase2<<<(NA / 32) * (NB / 32), 256, 0, stream>>>(Q, M, out);
}

// Round 2
// 75.654 us; speedup vs baseline: 1.0981x; 1.0981x over previous
//
#include <hip/hip_runtime.h>

// QuantumKernelMethod: out[i][j] = |phi(a_i)^dag M(b_j) phi(a_i)|
// phi = V(x)|0>, M = V(y) Z0 V(y)^dag. Reduced to real GEMM 1024x1024x512:
// out = |Q * M^T| with q_i = [Re Q, Im Q], m_j = [Re M, -Im M] (512 floats each).

#define NA 1024
#define NB 1024
#define KDIM 512

typedef __attribute__((ext_vector_type(8))) short bf16x8;
typedef __attribute__((ext_vector_type(4))) float f32x4;

__device__ __forceinline__ unsigned short f2bf(float x) {
    union { float f; unsigned u; } v; v.f = x;
    unsigned r = v.u + 0x7fffu + ((v.u >> 16) & 1u);  // RNE
    return (unsigned short)(r >> 16);
}

__device__ __forceinline__ uint4 pack8(const float* f) {
    uint4 u;
    u.x = (unsigned)f2bf(f[0]) | ((unsigned)f2bf(f[1]) << 16);
    u.y = (unsigned)f2bf(f[2]) | ((unsigned)f2bf(f[3]) << 16);
    u.z = (unsigned)f2bf(f[4]) | ((unsigned)f2bf(f[5]) << 16);
    u.w = (unsigned)f2bf(f[6]) | ((unsigned)f2bf(f[7]) << 16);
    return u;
}

// State: 16 complex amps, flat index = b0*8 + b1*4 + b2*2 + b3 (wire w -> bit 3-w)
__device__ __forceinline__ void ry_gate(float* sr, float* si, int w, float t) {
    float s, c; __sincosf(0.5f * t, &s, &c);
    int st = 8 >> w;
    #pragma unroll
    for (int b = 0; b < 16; ++b) {
        if (b & st) continue;
        int j = b | st;
        float r0 = sr[b], i0 = si[b], r1 = sr[j], i1 = si[j];
        sr[b] = c * r0 - s * r1;  si[b] = c * i0 - s * i1;
        sr[j] = s * r0 + c * r1;  si[j] = s * i0 + c * i1;
    }
}

__device__ __forceinline__ void rx_gate(float* sr, float* si, int w, float t) {
    float s, c; __sincosf(0.5f * t, &s, &c);
    int st = 8 >> w;
    #pragma unroll
    for (int b = 0; b < 16; ++b) {
        if (b & st) continue;
        int j = b | st;
        float r0 = sr[b], i0 = si[b], r1 = sr[j], i1 = si[j];
        sr[b] = c * r0 + s * i1;  si[b] = c * i0 - s * r1;
        sr[j] = c * r1 + s * i0;  si[j] = c * i1 - s * r0;
    }
}

__device__ __forceinline__ void rz_gate(float* sr, float* si, int w, float t) {
    float s, c; __sincosf(0.5f * t, &s, &c);
    int st = 8 >> w;
    #pragma unroll
    for (int b = 0; b < 16; ++b) {
        if (b & st) continue;
        int j = b | st;
        float r0 = sr[b], i0 = si[b], r1 = sr[j], i1 = si[j];
        sr[b] = c * r0 + s * i0;  si[b] = c * i0 - s * r0;
        sr[j] = c * r1 - s * i1;  si[j] = c * i1 + s * r1;
    }
}

__device__ __forceinline__ void cnot_gate(float* sr, float* si, int cw, int tw) {
    int cs = 8 >> cw, ts = 8 >> tw;
    #pragma unroll
    for (int b = 0; b < 16; ++b) {
        if ((b & cs) && !(b & ts)) {
            int j = b | ts;
            float tr = sr[b]; sr[b] = sr[j]; sr[j] = tr;
            float ti = si[b]; si[b] = si[j]; si[j] = ti;
        }
    }
}

__device__ __forceinline__ void ansatz(float* sr, float* si, const float* vec, const float* P) {
    #pragma unroll
    for (int q = 0; q < 4; ++q) ry_gate(sr, si, q, vec[q]);
    #pragma unroll
    for (int l = 0; l < 2; ++l) {
        #pragma unroll
        for (int q = 0; q < 4; ++q) {
            rx_gate(sr, si, q, P[l * 12 + q * 3 + 0]);
            ry_gate(sr, si, q, P[l * 12 + q * 3 + 1]);
            rz_gate(sr, si, q, P[l * 12 + q * 3 + 2]);
        }
        cnot_gate(sr, si, 0, 1);
        cnot_gate(sr, si, 1, 2);
        cnot_gate(sr, si, 2, 3);
        cnot_gate(sr, si, 3, 0);
    }
}

// Blocks [0,256): M-part, 4 y's per block (16 threads each simulate one basis col).
// Blocks [256,272): Q-part, 64 i's per block (one thread = one statevector sim).
// LDS layout: V[yl*520 + p2*32 + ri*16 + l]   (ri: 0=re, 1=im), yl stride 520
// -> yl groups start at banks {0,8,16,24}: float4 reads are bank-disjoint.
__global__ __launch_bounds__(64) void qkm_phase1(
    const float* __restrict__ a, const float* __restrict__ b,
    const float* __restrict__ params,
    uint4* __restrict__ Qv, uint4* __restrict__ Mv) {
    float P[24];
    #pragma unroll
    for (int j = 0; j < 24; ++j) P[j] = params[j];
    int tid = threadIdx.x;
    int blk = blockIdx.x;

    if (blk < 256) {
        __shared__ float V[4 * 520];
        int yl = tid >> 4, p = tid & 15;
        int y = (blk << 2) + yl;
        float sr[16], si[16];
        #pragma unroll
        for (int k = 0; k < 16; ++k) { sr[k] = (k == p) ? 1.f : 0.f; si[k] = 0.f; }
        float vec[4];
        #pragma unroll
        for (int q = 0; q < 4; ++q) vec[q] = b[y * 4 + q];
        ansatz(sr, si, vec, P);
        float* row = &V[yl * 520 + p * 32];
        #pragma unroll
        for (int c = 0; c < 4; ++c) {
            *(float4*)(row + 4 * c)      = *(float4*)(sr + 4 * c);
            *(float4*)(row + 16 + 4 * c) = *(float4*)(si + 4 * c);
        }
        __syncthreads();
        // Thread computes row k=p of M_y: M[k][l] = sum_p2 d_p2 v_p2[k] conj(v_p2[l])
        int k = p;
        float mr[16], mi[16];
        #pragma unroll
        for (int l = 0; l < 16; ++l) { mr[l] = 0.f; mi[l] = 0.f; }
        #pragma unroll
        for (int p2 = 0; p2 < 16; ++p2) {
            const float* r2 = &V[yl * 520 + p2 * 32];
            float d = (p2 & 8) ? -1.f : 1.f;  // Z0 sign: wire-0 bit = bit 3
            float ar = r2[k], ai = r2[16 + k];
            float dar = d * ar, dai = d * ai;
            #pragma unroll
            for (int c = 0; c < 4; ++c) {
                float4 brv = *(const float4*)(r2 + 4 * c);
                float4 biv = *(const float4*)(r2 + 16 + 4 * c);
                mr[c*4+0] += dar * brv.x + dai * biv.x;  mi[c*4+0] += dai * brv.x - dar * biv.x;
                mr[c*4+1] += dar * brv.y + dai * biv.y;  mi[c*4+1] += dai * brv.y - dar * biv.y;
                mr[c*4+2] += dar * brv.z + dai * biv.z;  mi[c*4+2] += dai * brv.z - dar * biv.z;
                mr[c*4+3] += dar * brv.w + dai * biv.w;  mi[c*4+3] += dai * brv.w - dar * biv.w;
            }
        }
        float ni[16];
        #pragma unroll
        for (int l = 0; l < 16; ++l) ni[l] = -mi[l];   // store -Im M
        uint4* d0 = Mv + y * 64 + k * 2;        // Re M at ushort offset k*16
        d0[0] = pack8(&mr[0]); d0[1] = pack8(&mr[8]);
        uint4* d1 = Mv + y * 64 + 32 + k * 2;   // -Im M at ushort offset 256+k*16
        d1[0] = pack8(&ni[0]); d1[1] = pack8(&ni[8]);
    } else {
        int i = ((blk - 256) << 6) + tid;
        float sr[16], si[16];
        #pragma unroll
        for (int k = 0; k < 16; ++k) { sr[k] = (k == 0) ? 1.f : 0.f; si[k] = 0.f; }
        float vec[4];
        #pragma unroll
        for (int q = 0; q < 4; ++q) vec[q] = a[i * 4 + q];
        ansatz(sr, si, vec, P);
        // Q[k][l] = conj(phi_k) phi_l: Re = rk*rl + ik*il, Im = rk*il - ik*rl
        #pragma unroll
        for (int k = 0; k < 16; ++k) {
            float t0[16], t1[16];
            float rk = sr[k], ik = si[k];
            #pragma unroll
            for (int l = 0; l < 16; ++l) {
                t0[l] = rk * sr[l] + ik * si[l];
                t1[l] = rk * si[l] - ik * sr[l];
            }
            uint4* d0 = Qv + i * 64 + k * 2;
            d0[0] = pack8(t0); d0[1] = pack8(t0 + 8);
            uint4* d1 = Qv + i * 64 + 32 + k * 2;
            d1[0] = pack8(t1); d1[1] = pack8(t1 + 8);
        }
    }
}

// Phase 2: out = |Q * M^T|, bf16 MFMA. 64x64 tile/block, 4 waves in 2x2,
// each wave a 32x32 sub-tile = 2x2 MFMA fragments. XCD-aware swizzle:
// xcd = blk&7 owns Q-row band [xcd*128, xcd*128+128) -> band stays in that L2.
__global__ __launch_bounds__(256) void qkm_phase2(
    const unsigned short* __restrict__ Q, const unsigned short* __restrict__ M,
    float* __restrict__ out) {
    int wave = threadIdx.x >> 6;
    int lane = threadIdx.x & 63;
    int blk = blockIdx.x;
    int xcd = blk & 7;
    int slot = blk >> 3;                 // [0,32)
    int bi = xcd * 2 + (slot >> 4);      // [0,16)
    int bj = slot & 15;                  // [0,16)
    int wi = wave >> 1, wj = wave & 1;
    int row0 = bi * 64 + wi * 32;
    int col0 = bj * 64 + wj * 32;
    int m16 = lane & 15;
    int quad = lane >> 4;

    const unsigned short* q0 = Q + (size_t)(row0 + m16) * KDIM + quad * 8;
    const unsigned short* q1 = q0 + 16 * KDIM;
    const unsigned short* m0 = M + (size_t)(col0 + m16) * KDIM + quad * 8;
    const unsigned short* m1 = m0 + 16 * KDIM;

    f32x4 a00 = {0.f,0.f,0.f,0.f}, a01 = {0.f,0.f,0.f,0.f};
    f32x4 a10 = {0.f,0.f,0.f,0.f}, a11 = {0.f,0.f,0.f,0.f};
    #pragma unroll 4
    for (int kk = 0; kk < 16; ++kk) {
        bf16x8 qa = *(const bf16x8*)(q0 + kk * 32);
        bf16x8 qb = *(const bf16x8*)(q1 + kk * 32);
        bf16x8 ma = *(const bf16x8*)(m0 + kk * 32);
        bf16x8 mb = *(const bf16x8*)(m1 + kk * 32);
        a00 = __builtin_amdgcn_mfma_f32_16x16x32_bf16(qa, ma, a00, 0, 0, 0);
        a01 = __builtin_amdgcn_mfma_f32_16x16x32_bf16(qa, mb, a01, 0, 0, 0);
        a10 = __builtin_amdgcn_mfma_f32_16x16x32_bf16(qb, ma, a10, 0, 0, 0);
        a11 = __builtin_amdgcn_mfma_f32_16x16x32_bf16(qb, mb, a11, 0, 0, 0);
    }
    // C/D layout: col = lane&15, row = quad*4 + r  [HW-verified]
    #pragma unroll
    for (int r = 0; r < 4; ++r) {
        int r0o = row0 + quad * 4 + r;
        int r1o = r0o + 16;
        out[r0o * NB + col0 + m16]      = fabsf(a00[r]);
        out[r0o * NB + col0 + 16 + m16] = fabsf(a01[r]);
        out[r1o * NB + col0 + m16]      = fabsf(a10[r]);
        out[r1o * NB + col0 + 16 + m16] = fabsf(a11[r]);
    }
}

extern "C" void kernel_launch(void* const* d_in, const int* in_sizes, int n_in,
                              void* d_out, int out_size, void* d_ws, size_t ws_size,
                              hipStream_t stream) {
    const float* a = (const float*)d_in[0];       // 1024 x 4
    const float* b = (const float*)d_in[1];       // 1024 x 4
    const float* params = (const float*)d_in[2];  // 2 x 4 x 3
    float* out = (float*)d_out;                   // 1024 x 1024

    unsigned short* Q = (unsigned short*)d_ws;            // NA x 512 bf16
    unsigned short* M = Q + (size_t)NA * KDIM;            // NB x 512 bf16

    qkm_phase1<<<256 + NA / 64, 64, 0, stream>>>(a, b, params, (uint4*)Q, (uint4*)M);
    qkm_phase2<<<256, 256, 0, stream>>>(Q, M, out);
}

// Round 3
// 70.830 us; speedup vs baseline: 1.1729x; 1.0681x over previous
//
#include <hip/hip_runtime.h>

// QuantumKernelMethod: out[i][j] = |tr(Q_i M_j)|
// Q_i = phi phi^T (phi = V(a_i)|0>), M_j = V(b_j) Z0 V(b_j)^dag = I - 2P,
// P = sum_{p: wire0bit=1} w_p w_p^dag (8 basis sims per y).
// Hermitian pack (K=256): S[k][l] = diag | sqrt2*Re (k<l) | sqrt2*Im mirror (k>l);
// dot(S_Q, S_M) = tr(QM) exactly. out = |Q(1024x256) * M(1024x256)^T|.

#define NA 1024
#define NB 1024
#define KD 256
#define RT2 1.41421356237f

typedef __attribute__((ext_vector_type(8))) short bf16x8;
typedef __attribute__((ext_vector_type(4))) float f32x4;

__device__ __forceinline__ unsigned short f2bf(float x) {
    union { float f; unsigned u; } v; v.f = x;
    unsigned r = v.u + 0x7fffu + ((v.u >> 16) & 1u);  // RNE
    return (unsigned short)(r >> 16);
}

__device__ __forceinline__ uint4 pack8(const float* f) {
    uint4 u;
    u.x = (unsigned)f2bf(f[0]) | ((unsigned)f2bf(f[1]) << 16);
    u.y = (unsigned)f2bf(f[2]) | ((unsigned)f2bf(f[3]) << 16);
    u.z = (unsigned)f2bf(f[4]) | ((unsigned)f2bf(f[5]) << 16);
    u.w = (unsigned)f2bf(f[6]) | ((unsigned)f2bf(f[7]) << 16);
    return u;
}

// State: 16 complex amps, flat index = b0*8 + b1*4 + b2*2 + b3 (wire w -> bit 3-w)
__device__ __forceinline__ void ry_gate(float* sr, float* si, int w, float t) {
    float s, c; __sincosf(0.5f * t, &s, &c);
    int st = 8 >> w;
    #pragma unroll
    for (int b = 0; b < 16; ++b) {
        if (b & st) continue;
        int j = b | st;
        float r0 = sr[b], i0 = si[b], r1 = sr[j], i1 = si[j];
        sr[b] = c * r0 - s * r1;  si[b] = c * i0 - s * i1;
        sr[j] = s * r0 + c * r1;  si[j] = s * i0 + c * i1;
    }
}

__device__ __forceinline__ void rx_gate(float* sr, float* si, int w, float t) {
    float s, c; __sincosf(0.5f * t, &s, &c);
    int st = 8 >> w;
    #pragma unroll
    for (int b = 0; b < 16; ++b) {
        if (b & st) continue;
        int j = b | st;
        float r0 = sr[b], i0 = si[b], r1 = sr[j], i1 = si[j];
        sr[b] = c * r0 + s * i1;  si[b] = c * i0 - s * r1;
        sr[j] = c * r1 + s * i0;  si[j] = c * i1 - s * r0;
    }
}

__device__ __forceinline__ void rz_gate(float* sr, float* si, int w, float t) {
    float s, c; __sincosf(0.5f * t, &s, &c);
    int st = 8 >> w;
    #pragma unroll
    for (int b = 0; b < 16; ++b) {
        if (b & st) continue;
        int j = b | st;
        float r0 = sr[b], i0 = si[b], r1 = sr[j], i1 = si[j];
        sr[b] = c * r0 + s * i0;  si[b] = c * i0 - s * r0;
        sr[j] = c * r1 - s * i1;  si[j] = c * i1 + s * r1;
    }
}

__device__ __forceinline__ void cnot_gate(float* sr, float* si, int cw, int tw) {
    int cs = 8 >> cw, ts = 8 >> tw;
    #pragma unroll
    for (int b = 0; b < 16; ++b) {
        if ((b & cs) && !(b & ts)) {
            int j = b | ts;
            float tr = sr[b]; sr[b] = sr[j]; sr[j] = tr;
            float ti = si[b]; si[b] = si[j]; si[j] = ti;
        }
    }
}

__device__ __forceinline__ void ansatz(float* sr, float* si, const float* vec, const float* P) {
    #pragma unroll
    for (int q = 0; q < 4; ++q) ry_gate(sr, si, q, vec[q]);
    #pragma unroll
    for (int l = 0; l < 2; ++l) {
        #pragma unroll
        for (int q = 0; q < 4; ++q) {
            rx_gate(sr, si, q, P[l * 12 + q * 3 + 0]);
            ry_gate(sr, si, q, P[l * 12 + q * 3 + 1]);
            rz_gate(sr, si, q, P[l * 12 + q * 3 + 2]);
        }
        cnot_gate(sr, si, 0, 1);
        cnot_gate(sr, si, 1, 2);
        cnot_gate(sr, si, 2, 3);
        cnot_gate(sr, si, 3, 0);
    }
}

// Blocks [0,128): M-part, 8 y's/block, 8 threads per y each simulating one
//   basis state p=8+t (wire0 bit set). LDS W[l][sim]: writes lane-contiguous,
//   reads broadcast across t (free) / 2-way across g (free).
// Blocks [128,144): Q-part, 64 i's/block, one thread = one statevector sim.
__global__ __launch_bounds__(64) void qkm_phase1(
    const float* __restrict__ a, const float* __restrict__ b,
    const float* __restrict__ params,
    uint4* __restrict__ Qv, uint4* __restrict__ Mv) {
    float P[24];
    #pragma unroll
    for (int j = 0; j < 24; ++j) P[j] = params[j];
    int tid = threadIdx.x;
    int blk = blockIdx.x;

    if (blk < 128) {
        __shared__ float Wr[16][64];
        __shared__ float Wi[16][64];
        int g = tid >> 3, t = tid & 7;
        int y = (blk << 3) + g;
        float sr[16], si[16];
        #pragma unroll
        for (int k = 0; k < 16; ++k) { sr[k] = (k == 8 + t) ? 1.f : 0.f; si[k] = 0.f; }
        float vec[4];
        #pragma unroll
        for (int q = 0; q < 4; ++q) vec[q] = b[y * 4 + q];
        ansatz(sr, si, vec, P);
        #pragma unroll
        for (int l = 0; l < 16; ++l) { Wr[l][tid] = sr[l]; Wi[l][tid] = si[l]; }
        __syncthreads();
        int base = g << 3;
        // Thread computes rows k = 2t, 2t+1 of S_M for its y.
        #pragma unroll
        for (int kr = 0; kr < 2; ++kr) {
            int k = 2 * t + kr;
            float re[16], im[16];
            #pragma unroll
            for (int l = 0; l < 16; ++l) { re[l] = 0.f; im[l] = 0.f; }
            #pragma unroll
            for (int p2 = 0; p2 < 8; ++p2) {
                float wrk = Wr[k][base + p2], wik = Wi[k][base + p2];
                #pragma unroll
                for (int l = 0; l < 16; ++l) {
                    float wrl = Wr[l][base + p2], wil = Wi[l][base + p2];
                    re[l] += wrk * wrl + wik * wil;   // Re P_kl (sum over sims)
                    im[l] += wil * wrk - wrl * wik;   // Im P_lk
                }
            }
            float row[16];
            #pragma unroll
            for (int l = 0; l < 16; ++l) {
                float off = (l < k) ? im[l] : re[l];
                row[l] = (l == k) ? (1.f - 2.f * re[l]) : (-2.f * RT2 * off);
            }
            uint4* d = Mv + y * 32 + k * 2;
            d[0] = pack8(row); d[1] = pack8(row + 8);
        }
    } else if (blk < 144) {
        int i = ((blk - 128) << 6) + tid;
        float sr[16], si[16];
        #pragma unroll
        for (int k = 0; k < 16; ++k) { sr[k] = (k == 0) ? 1.f : 0.f; si[k] = 0.f; }
        float vec[4];
        #pragma unroll
        for (int q = 0; q < 4; ++q) vec[q] = a[i * 4 + q];
        ansatz(sr, si, vec, P);
        // Q = phi phi^dag: Re Q_kl = rk*rl + ik*il; Im Q_lk = il*rk - rl*ik
        #pragma unroll
        for (int k = 0; k < 16; ++k) {
            float rk = sr[k], ik = si[k];
            float row[16];
            #pragma unroll
            for (int l = 0; l < 16; ++l) {
                if (l < k)       row[l] = RT2 * (si[l] * rk - sr[l] * ik);
                else if (l == k) row[l] = rk * rk + ik * ik;
                else             row[l] = RT2 * (rk * sr[l] + ik * si[l]);
            }
            uint4* d = Qv + i * 32 + k * 2;
            d[0] = pack8(row); d[1] = pack8(row + 8);
        }
    }
}

// Phase 2: out = |Q * M^T|, bf16 MFMA, K=256. 64x64 tile/block, 4 waves 2x2,
// each wave 32x32 = 2x2 fragments. XCD swizzle: xcd=blk&7 owns a Q-row band.
__global__ __launch_bounds__(256) void qkm_phase2(
    const unsigned short* __restrict__ Q, const unsigned short* __restrict__ M,
    float* __restrict__ out) {
    int wave = threadIdx.x >> 6;
    int lane = threadIdx.x & 63;
    int blk = blockIdx.x;
    int xcd = blk & 7;
    int slot = blk >> 3;                 // [0,32)
    int bi = xcd * 2 + (slot >> 4);      // [0,16)
    int bj = slot & 15;                  // [0,16)
    int wi = wave >> 1, wj = wave & 1;
    int row0 = bi * 64 + wi * 32;
    int col0 = bj * 64 + wj * 32;
    int m16 = lane & 15;
    int quad = lane >> 4;

    const unsigned short* q0 = Q + (size_t)(row0 + m16) * KD + quad * 8;
    const unsigned short* q1 = q0 + 16 * KD;
    const unsigned short* m0 = M + (size_t)(col0 + m16) * KD + quad * 8;
    const unsigned short* m1 = m0 + 16 * KD;

    f32x4 a00 = {0.f,0.f,0.f,0.f}, a01 = {0.f,0.f,0.f,0.f};
    f32x4 a10 = {0.f,0.f,0.f,0.f}, a11 = {0.f,0.f,0.f,0.f};
    #pragma unroll
    for (int kk = 0; kk < 8; ++kk) {
        bf16x8 qa = *(const bf16x8*)(q0 + kk * 32);
        bf16x8 qb = *(const bf16x8*)(q1 + kk * 32);
        bf16x8 ma = *(const bf16x8*)(m0 + kk * 32);
        bf16x8 mb = *(const bf16x8*)(m1 + kk * 32);
        a00 = __builtin_amdgcn_mfma_f32_16x16x32_bf16(qa, ma, a00, 0, 0, 0);
        a01 = __builtin_amdgcn_mfma_f32_16x16x32_bf16(qa, mb, a01, 0, 0, 0);
        a10 = __builtin_amdgcn_mfma_f32_16x16x32_bf16(qb, ma, a10, 0, 0, 0);
        a11 = __builtin_amdgcn_mfma_f32_16x16x32_bf16(qb, mb, a11, 0, 0, 0);
    }
    // C/D layout: col = lane&15, row = quad*4 + r  [HW-verified]
    #pragma unroll
    for (int r = 0; r < 4; ++r) {
        int r0o = row0 + quad * 4 + r;
        int r1o = r0o + 16;
        out[r0o * NB + col0 + m16]      = fabsf(a00[r]);
        out[r0o * NB + col0 + 16 + m16] = fabsf(a01[r]);
        out[r1o * NB + col0 + m16]      = fabsf(a10[r]);
        out[r1o * NB + col0 + 16 + m16] = fabsf(a11[r]);
    }
}

extern "C" void kernel_launch(void* const* d_in, const int* in_sizes, int n_in,
                              void* d_out, int out_size, void* d_ws, size_t ws_size,
                              hipStream_t stream) {
    const float* a = (const float*)d_in[0];       // 1024 x 4
    const float* b = (const float*)d_in[1];       // 1024 x 4
    const float* params = (const float*)d_in[2];  // 2 x 4 x 3
    float* out = (float*)d_out;                   // 1024 x 1024

    unsigned short* Q = (unsigned short*)d_ws;            // NA x 256 bf16
    unsigned short* M = Q + (size_t)NA * KD;              // NB x 256 bf16

    qkm_phase1<<<144, 64, 0, stream>>>(a, b, params, (uint4*)Q, (uint4*)M);
    qkm_phase2<<<256, 256, 0, stream>>>(Q, M, out);
}